// Round 10
// baseline (351.433 us; speedup 1.0000x reference)
//
#include <hip/hip_runtime.h>
#include <hip/hip_bf16.h>

typedef __hip_bfloat16 BF;
typedef __attribute__((ext_vector_type(8))) short bf16x8;
typedef __attribute__((ext_vector_type(4))) float f32x4;

// B=2, C=128, H=W=128, K=8, STRIDE=2, DIL=2, NH=8, dh=16, HID=170, Hc=Wc=64
// fp32 in / fp32 out. MFMA bf16 GEMMs, M=16 tiles. ws layout as R9.

// ---- K0: tiled transpose x (B,C,H,W) -> xt (B,HW,C) ----
__global__ void k_tin(const float* __restrict__ x, float* __restrict__ xt){
  __shared__ float tile[32][33];
  const int b = blockIdx.z;
  const int pb = blockIdx.x * 32;
  const int cb = blockIdx.y * 32;
  const int tx = threadIdx.x, ty = threadIdx.y;
  #pragma unroll
  for(int r = 0; r < 32; r += 8)
    tile[ty+r][tx] = x[(size_t)(b*128 + cb+ty+r)*16384 + pb + tx];
  __syncthreads();
  #pragma unroll
  for(int r = 0; r < 32; r += 8)
    xt[(size_t)((b<<14) + pb + ty + r)*128 + cb + tx] = tile[tx][ty+r];
}

// ---- K1: pack weights to MFMA-B fragment layout, bf16 (same as R9) ----
__global__ void k_wt(const float* __restrict__ qkv_w, const float* __restrict__ proj_w,
                     const float* __restrict__ fc1_w, const float* __restrict__ fc2_w,
                     BF* __restrict__ pk){
  const int idx = blockIdx.x * 256 + threadIdx.x;
  if(idx >= 112640) return;
  float val;
  if(idx < 49152){
    const int reg = idx >> 14, l = idx & 16383;
    const int j = l & 7, q = (l>>3)&3, n = (l>>5)&127, s = l>>12;
    val = qkv_w[(reg*128 + n)*128 + (s*32 + q*8 + j)];
  } else if(idx < 65536){
    const int l = idx - 49152;
    const int j = l&7, q=(l>>3)&3, n=(l>>5)&127, s=l>>12;
    val = proj_w[n*128 + (s*32+q*8+j)];
  } else if(idx < 88064){
    const int l = idx - 65536;
    const int j = l&7, q=(l>>3)&3, rem = l>>5;
    const int n = rem % 176, s = rem / 176;
    const int k = s*32+q*8+j;
    val = (n < 170) ? fc1_w[n*128 + k] : 0.f;
  } else {
    const int l = idx - 88064;
    const int j = l&7, q=(l>>3)&3, n=(l>>5)&127, s=l>>12;
    const int k = s*32+q*8+j;
    val = (k < 170) ? fc2_w[n*170 + k] : 0.f;
  }
  pk[idx] = __float2bfloat16(val);
}

// ---- K2: coarse k,v via MFMA, M=16 (16 coarse px / block) ----
__global__ void __launch_bounds__(128)
k_kv(const float* __restrict__ xt,
     const BF* __restrict__ packK, const BF* __restrict__ packV,
     const float* __restrict__ qkv_b,
     const float* __restrict__ kg, const float* __restrict__ kb,
     const float* __restrict__ n1g, const float* __restrict__ n1b,
     float* __restrict__ kcb, float* __restrict__ vcb){
  __shared__ BF Abuf[16*136];
  __shared__ float red[64];
  const int tid = threadIdx.x, wave = tid>>6, lane = tid&63;
  const int l15 = lane&15, q4 = lane>>4;
  const int bx = blockIdx.x;
  float xv[16];
  #pragma unroll
  for(int r = 0; r < 16; r++){
    const int cp = bx*16 + r;
    const int bb = cp>>12, rm = cp&4095, ic = rm>>6, jc = rm&63;
    xv[r] = xt[((size_t)(bb*16384 + 2*ic*128 + 2*jc))*128 + tid];
  }
  // LN1: sum
  float v[16];
  #pragma unroll
  for(int r = 0; r < 16; r++) v[r] = xv[r];
  #pragma unroll
  for(int s = 1; s < 64; s <<= 1){
    #pragma unroll
    for(int r = 0; r < 16; r++) v[r] += __shfl_xor(v[r], s);
  }
  __syncthreads();
  if(lane == 0){ for(int r = 0; r < 16; r++) red[wave*16 + r] = v[r]; }
  __syncthreads();
  #pragma unroll
  for(int r = 0; r < 16; r++) v[r] = red[r] + red[16 + r];
  float xc[16], sq[16];
  #pragma unroll
  for(int r = 0; r < 16; r++){ xc[r] = xv[r] - v[r]*(1.f/128.f); sq[r] = xc[r]*xc[r]; }
  #pragma unroll
  for(int s = 1; s < 64; s <<= 1){
    #pragma unroll
    for(int r = 0; r < 16; r++) sq[r] += __shfl_xor(sq[r], s);
  }
  __syncthreads();
  if(lane == 0){ for(int r = 0; r < 16; r++) red[wave*16 + r] = sq[r]; }
  __syncthreads();
  #pragma unroll
  for(int r = 0; r < 16; r++) sq[r] = red[r] + red[16 + r];
  {
    const float g = n1g[tid], be = n1b[tid];
    #pragma unroll
    for(int r = 0; r < 16; r++)
      Abuf[r*136 + tid] = __float2bfloat16(xc[r]*rsqrtf(sq[r]*(1.f/128.f)+1e-6f)*g + be);
  }
  __syncthreads();
  bf16x8 af[4];
  #pragma unroll
  for(int s = 0; s < 4; s++) af[s] = *(const bf16x8*)&Abuf[l15*136 + s*32 + q4*8];

  // ---- k GEMM (8 tiles: wave*4+nt) ----
  f32x4 ka[4];
  #pragma unroll
  for(int nt = 0; nt < 4; nt++){ ka[nt][0]=0.f; ka[nt][1]=0.f; ka[nt][2]=0.f; ka[nt][3]=0.f; }
  #pragma unroll
  for(int nt = 0; nt < 4; nt++){
    const int col = (wave*4+nt)*16 + l15;
    #pragma unroll
    for(int s = 0; s < 4; s++){
      bf16x8 bw = *(const bf16x8*)&packK[((s*128 + col)*4 + q4)*8];
      ka[nt] = __builtin_amdgcn_mfma_f32_16x16x32_bf16(af[s], bw, ka[nt], 0,0,0);
    }
  }
  float s1[4], s2[4];
  #pragma unroll
  for(int r = 0; r < 4; r++){ s1[r]=0.f; s2[r]=0.f; }
  #pragma unroll
  for(int nt = 0; nt < 4; nt++){
    const float cb2 = qkv_b[128 + (wave*4+nt)*16 + l15];
    #pragma unroll
    for(int r = 0; r < 4; r++){
      const float vv = ka[nt][r] + cb2;
      ka[nt][r] = vv; s1[r] += vv; s2[r] += vv*vv;
    }
  }
  // rowred (2 waves)
  #pragma unroll
  for(int m = 1; m < 16; m <<= 1){
    #pragma unroll
    for(int r = 0; r < 4; r++){ s1[r] += __shfl_xor(s1[r], m); s2[r] += __shfl_xor(s2[r], m); }
  }
  __syncthreads();
  if(l15 == 0){
    #pragma unroll
    for(int r = 0; r < 4; r++){
      red[wave*32 + q4*4 + r]      = s1[r];
      red[wave*32 + 16 + q4*4 + r] = s2[r];
    }
  }
  __syncthreads();
  #pragma unroll
  for(int r = 0; r < 4; r++){
    s1[r] = red[q4*4 + r]      + red[32 + q4*4 + r];
    s2[r] = red[16 + q4*4 + r] + red[48 + q4*4 + r];
  }
  #pragma unroll
  for(int nt = 0; nt < 4; nt++){
    const int col = (wave*4+nt)*16 + l15;
    const float g = kg[col], be = kb[col];
    #pragma unroll
    for(int r = 0; r < 4; r++){
      const float mu = s1[r]*(1.f/128.f);
      const float var = s2[r]*(1.f/128.f) - mu*mu;
      kcb[(size_t)(bx*16 + q4*4 + r)*128 + col] = (ka[nt][r]-mu)*rsqrtf(var+1e-6f)*g + be;
    }
  }
  // ---- v GEMM ----
  #pragma unroll
  for(int nt = 0; nt < 4; nt++){ ka[nt][0]=0.f; ka[nt][1]=0.f; ka[nt][2]=0.f; ka[nt][3]=0.f; }
  #pragma unroll
  for(int nt = 0; nt < 4; nt++){
    const int col = (wave*4+nt)*16 + l15;
    #pragma unroll
    for(int s = 0; s < 4; s++){
      bf16x8 bw = *(const bf16x8*)&packV[((s*128 + col)*4 + q4)*8];
      ka[nt] = __builtin_amdgcn_mfma_f32_16x16x32_bf16(af[s], bw, ka[nt], 0,0,0);
    }
  }
  #pragma unroll
  for(int nt = 0; nt < 4; nt++){
    const int col = (wave*4+nt)*16 + l15;
    const float bv = qkv_b[256 + col];
    #pragma unroll
    for(int r = 0; r < 4; r++)
      vcb[(size_t)(bx*16 + q4*4 + r)*128 + col] = ka[nt][r] + bv;
  }
}

// ---- K3: fused 4-cell (16 pixel) block, wave-local attention ----
__global__ void __launch_bounds__(256)
k_cell(const float* __restrict__ xt_in,
       const BF* __restrict__ packQ, const BF* __restrict__ packP,
       const BF* __restrict__ packF1, const BF* __restrict__ packF2,
       const float* __restrict__ qkv_b,
       const float* __restrict__ qg, const float* __restrict__ qb,
       const float* __restrict__ n1g, const float* __restrict__ n1b,
       const float* __restrict__ proj_b,
       const float* __restrict__ ls1, const float* __restrict__ ls2,
       const float* __restrict__ n2g, const float* __restrict__ n2b,
       const float* __restrict__ fc1_b,
       const float* __restrict__ mg, const float* __restrict__ mb,
       const float* __restrict__ fc2_b,
       const float* __restrict__ kcb, const float* __restrict__ vcb,
       float* __restrict__ xt_out){
  __shared__ BF Abuf[16*200];       // stride 200 bf16 = 400 B: 16B-aligned, 2-way banks
  __shared__ float4 qnL[4*137];     // [cell][head(stride 17)][d]
  __shared__ float red[128];
  const int tid = threadIdx.x, wave = tid>>6, lane = tid&63;
  const int l15 = lane&15, q4 = lane>>4;
  { uint32_t* az = (uint32_t*)Abuf; for(int i = tid; i < 1600; i += 256) az[i] = 0u; }
  const int bx = blockIdx.x;        // 2048
  const int b = bx>>10, rem = bx&1023, cic = rem>>5, cjc = rem&31;
  const size_t base = (size_t)b * 16384 * 128;

  // ---- LN1 (threads: c = tid&127, half = tid>>7 owns rows half*8 + 0..7) ----
  const int c = tid & 127, half = tid >> 7;
  {
    float xv[8];
    #pragma unroll
    for(int r = 0; r < 8; r++){
      const int row = half*8 + r, cell = row>>2, sub = row&3;
      const int ic = 2*cic + (cell>>1), jc = 2*cjc + (cell&1);
      const int h = 2*ic + (sub>>1), wd = 2*jc + (sub&1);
      xv[r] = xt_in[base + (size_t)(h*128 + wd)*128 + c];
    }
    float v[8];
    #pragma unroll
    for(int r = 0; r < 8; r++) v[r] = xv[r];
    #pragma unroll
    for(int s = 1; s < 64; s <<= 1){
      #pragma unroll
      for(int r = 0; r < 8; r++) v[r] += __shfl_xor(v[r], s);
    }
    __syncthreads();
    if(lane == 0){ for(int r = 0; r < 8; r++) red[wave*8 + r] = v[r]; }
    __syncthreads();
    #pragma unroll
    for(int r = 0; r < 8; r++) v[r] = red[(half*2)*8 + r] + red[(half*2+1)*8 + r];
    float xc[8], sq[8];
    #pragma unroll
    for(int r = 0; r < 8; r++){ xc[r] = xv[r] - v[r]*(1.f/128.f); sq[r] = xc[r]*xc[r]; }
    #pragma unroll
    for(int s = 1; s < 64; s <<= 1){
      #pragma unroll
      for(int r = 0; r < 8; r++) sq[r] += __shfl_xor(sq[r], s);
    }
    __syncthreads();
    if(lane == 0){ for(int r = 0; r < 8; r++) red[wave*8 + r] = sq[r]; }
    __syncthreads();
    #pragma unroll
    for(int r = 0; r < 8; r++) sq[r] = red[(half*2)*8 + r] + red[(half*2+1)*8 + r];
    const float g = n1g[c], be = n1b[c];
    #pragma unroll
    for(int r = 0; r < 8; r++)
      Abuf[(half*8+r)*200 + c] = __float2bfloat16(xc[r]*rsqrtf(sq[r]*(1.f/128.f)+1e-6f)*g + be);
  }
  __syncthreads();

  // ---- q GEMM (tiles {wave, wave+4} = heads) + q-LN -> qnL ----
  {
    bf16x8 af[4];
    #pragma unroll
    for(int s = 0; s < 4; s++) af[s] = *(const bf16x8*)&Abuf[l15*200 + s*32 + q4*8];
    f32x4 qa[2];
    #pragma unroll
    for(int nt = 0; nt < 2; nt++){ qa[nt][0]=0.f; qa[nt][1]=0.f; qa[nt][2]=0.f; qa[nt][3]=0.f; }
    #pragma unroll
    for(int nt = 0; nt < 2; nt++){
      const int col = (wave + 4*nt)*16 + l15;
      #pragma unroll
      for(int s = 0; s < 4; s++){
        bf16x8 bw = *(const bf16x8*)&packQ[((s*128 + col)*4 + q4)*8];
        qa[nt] = __builtin_amdgcn_mfma_f32_16x16x32_bf16(af[s], bw, qa[nt], 0,0,0);
      }
    }
    float s1[4], s2[4];
    #pragma unroll
    for(int r = 0; r < 4; r++){ s1[r]=0.f; s2[r]=0.f; }
    #pragma unroll
    for(int nt = 0; nt < 2; nt++){
      const float cb2 = qkv_b[(wave + 4*nt)*16 + l15];
      #pragma unroll
      for(int r = 0; r < 4; r++){
        const float vv = qa[nt][r] + cb2;
        qa[nt][r] = vv; s1[r] += vv; s2[r] += vv*vv;
      }
    }
    // rowred4
    #pragma unroll
    for(int m = 1; m < 16; m <<= 1){
      #pragma unroll
      for(int r = 0; r < 4; r++){ s1[r] += __shfl_xor(s1[r], m); s2[r] += __shfl_xor(s2[r], m); }
    }
    __syncthreads();
    if(l15 == 0){
      #pragma unroll
      for(int r = 0; r < 4; r++){
        red[wave*32 + q4*4 + r]      = s1[r];
        red[wave*32 + 16 + q4*4 + r] = s2[r];
      }
    }
    __syncthreads();
    #pragma unroll
    for(int r = 0; r < 4; r++){
      s1[r] = red[q4*4+r] + red[32+q4*4+r] + red[64+q4*4+r] + red[96+q4*4+r];
      s2[r] = red[16+q4*4+r] + red[48+q4*4+r] + red[80+q4*4+r] + red[112+q4*4+r];
    }
    float mu[4], rs[4];
    #pragma unroll
    for(int r = 0; r < 4; r++){
      mu[r] = s1[r]*(1.f/128.f);
      rs[r] = rsqrtf(s2[r]*(1.f/128.f) - mu[r]*mu[r] + 1e-6f);
    }
    #pragma unroll
    for(int nt = 0; nt < 2; nt++){
      const int n = wave + 4*nt;
      const int col = n*16 + l15;
      const float g = qg[col], be = qb[col];
      float4 t;
      t.x = (qa[nt][0]-mu[0])*rs[0]*g + be;
      t.y = (qa[nt][1]-mu[1])*rs[1]*g + be;
      t.z = (qa[nt][2]-mu[2])*rs[2]*g + be;
      t.w = (qa[nt][3]-mu[3])*rs[3]*g + be;
      qnL[q4*137 + n*17 + l15] = t;   // cell = q4, d = l15
    }
  }
  __syncthreads();

  // ---- attention: wave w owns cell w; no intra-phase barriers ----
  float4 a0, a1;
  float xh[2][4];
  {
    const int aw = wave;
    const int ic_a = 2*cic + (aw>>1), jc_a = 2*cjc + (aw&1);
    int ci_reg;
    {
      const int i = lane>>3, j = lane&7;
      const int ri = ic_a + 2*i - 8, rj = jc_a + 2*j - 8;
      ci_reg = (ri>=0 && ri<64 && rj>=0 && rj<64) ? ((b*4096 + ri*64 + rj)*128) : -1;
    }
    const int hn = lane>>3, jj = lane&7;
    int cis[8]; bool cval[8];
    #pragma unroll
    for(int rep = 0; rep < 8; rep++){
      const int cc = __shfl(ci_reg, rep*8 + jj);
      cval[rep] = (cc >= 0); cis[rep] = (cc < 0) ? 0 : cc;
    }
    float4 s[8];
    #pragma unroll
    for(int rep = 0; rep < 8; rep++){ s[rep].x=0.f; s[rep].y=0.f; s[rep].z=0.f; s[rep].w=0.f; }
    #pragma unroll
    for(int d = 0; d < 16; d++){
      const float4 qf = qnL[aw*137 + hn*17 + d];
      #pragma unroll
      for(int rep = 0; rep < 8; rep++){
        const float kv = kcb[cis[rep] + hn*16 + d];
        s[rep].x += qf.x*kv; s[rep].y += qf.y*kv; s[rep].z += qf.z*kv; s[rep].w += qf.w*kv;
      }
    }
    #pragma unroll
    for(int rep = 0; rep < 8; rep++){
      if(cval[rep]){ s[rep].x *= 0.25f; s[rep].y *= 0.25f; s[rep].z *= 0.25f; s[rep].w *= 0.25f; }
      else { s[rep].x = -1e30f; s[rep].y = -1e30f; s[rep].z = -1e30f; s[rep].w = -1e30f; }
    }
    // softmax over 64 nb (8 reps in-lane + 8 jj lanes)
    float4 m = s[0];
    #pragma unroll
    for(int rep = 1; rep < 8; rep++){
      m.x = fmaxf(m.x, s[rep].x); m.y = fmaxf(m.y, s[rep].y);
      m.z = fmaxf(m.z, s[rep].z); m.w = fmaxf(m.w, s[rep].w);
    }
    #pragma unroll
    for(int msk = 1; msk < 8; msk <<= 1){
      m.x = fmaxf(m.x, __shfl_xor(m.x, msk));
      m.y = fmaxf(m.y, __shfl_xor(m.y, msk));
      m.z = fmaxf(m.z, __shfl_xor(m.z, msk));
      m.w = fmaxf(m.w, __shfl_xor(m.w, msk));
    }
    float4 ssum; ssum.x=0.f; ssum.y=0.f; ssum.z=0.f; ssum.w=0.f;
    #pragma unroll
    for(int rep = 0; rep < 8; rep++){
      s[rep].x = __expf(s[rep].x - m.x); s[rep].y = __expf(s[rep].y - m.y);
      s[rep].z = __expf(s[rep].z - m.z); s[rep].w = __expf(s[rep].w - m.w);
      ssum.x += s[rep].x; ssum.y += s[rep].y; ssum.z += s[rep].z; ssum.w += s[rep].w;
    }
    #pragma unroll
    for(int msk = 1; msk < 8; msk <<= 1){
      ssum.x += __shfl_xor(ssum.x, msk); ssum.y += __shfl_xor(ssum.y, msk);
      ssum.z += __shfl_xor(ssum.z, msk); ssum.w += __shfl_xor(ssum.w, msk);
    }
    const float4 inv = {1.f/ssum.x, 1.f/ssum.y, 1.f/ssum.z, 1.f/ssum.w};
    #pragma unroll
    for(int rep = 0; rep < 8; rep++){
      s[rep].x *= inv.x; s[rep].y *= inv.y; s[rep].z *= inv.z; s[rep].w *= inv.w;
    }
    // PV: lane (hn, jj) -> channels c0 = hn*16 + 2jj, c0+1 for 4 pixels
    const int c0 = hn*16 + 2*jj;
    a0.x=0.f; a0.y=0.f; a0.z=0.f; a0.w=0.f;
    a1.x=0.f; a1.y=0.f; a1.z=0.f; a1.w=0.f;
    #pragma unroll
    for(int nb = 0; nb < 64; nb++){
      const int ci = __shfl(ci_reg, nb);
      const int cs = (ci < 0) ? 0 : ci;
      const int src = (lane & 56) | (nb & 7);
      float4 p;
      p.x = __shfl(s[nb>>3].x, src); p.y = __shfl(s[nb>>3].y, src);
      p.z = __shfl(s[nb>>3].z, src); p.w = __shfl(s[nb>>3].w, src);
      const float v0 = vcb[cs + c0], v1 = vcb[cs + c0 + 1];
      a0.x += p.x*v0; a0.y += p.y*v0; a0.z += p.z*v0; a0.w += p.w*v0;
      a1.x += p.x*v1; a1.y += p.y*v1; a1.z += p.z*v1; a1.w += p.w*v1;
    }
    // write ao -> Abuf (rows aw*4+pix), packed bf16 pairs
    {
      const float av0[4] = {a0.x, a0.y, a0.z, a0.w};
      const float av1[4] = {a1.x, a1.y, a1.z, a1.w};
      #pragma unroll
      for(int pix = 0; pix < 4; pix++){
        BF b0 = __float2bfloat16(av0[pix]);
        BF b1 = __float2bfloat16(av1[pix]);
        const uint32_t pack = (uint32_t)(*(unsigned short*)&b0)
                            | ((uint32_t)(*(unsigned short*)&b1) << 16);
        *(uint32_t*)&Abuf[(aw*4 + pix)*200 + c0] = pack;
      }
    }
  }
  __syncthreads();

  // residual row pointers for this lane's C-layout rows (cell = q4, sub = r)
  size_t prowC[4];
  {
    const int ic2 = 2*cic + (q4>>1), jc2 = 2*cjc + (q4&1);
    #pragma unroll
    for(int r = 0; r < 4; r++){
      const int h = 2*ic2 + (r>>1), wd = 2*jc2 + (r&1);
      prowC[r] = base + (size_t)(h*128 + wd)*128;
    }
  }

  // ---- proj GEMM + ls1*res -> xh ; LN2 -> Abuf ----
  {
    bf16x8 af[4];
    #pragma unroll
    for(int s = 0; s < 4; s++) af[s] = *(const bf16x8*)&Abuf[l15*200 + s*32 + q4*8];
    f32x4 pa[2];
    #pragma unroll
    for(int nt = 0; nt < 2; nt++){ pa[nt][0]=0.f; pa[nt][1]=0.f; pa[nt][2]=0.f; pa[nt][3]=0.f; }
    #pragma unroll
    for(int nt = 0; nt < 2; nt++){
      const int col = (wave + 4*nt)*16 + l15;
      #pragma unroll
      for(int s = 0; s < 4; s++){
        bf16x8 bw = *(const bf16x8*)&packP[((s*128 + col)*4 + q4)*8];
        pa[nt] = __builtin_amdgcn_mfma_f32_16x16x32_bf16(af[s], bw, pa[nt], 0,0,0);
      }
    }
    float s1[4], s2[4];
    #pragma unroll
    for(int r = 0; r < 4; r++){ s1[r]=0.f; s2[r]=0.f; }
    #pragma unroll
    for(int nt = 0; nt < 2; nt++){
      const int col = (wave + 4*nt)*16 + l15;
      const float bp = proj_b[col], l1 = ls1[col];
      #pragma unroll
      for(int r = 0; r < 4; r++){
        const float xvv = xt_in[prowC[r] + col];
        const float hx = xvv + l1*(pa[nt][r] + bp);
        xh[nt][r] = hx; s1[r] += hx; s2[r] += hx*hx;
      }
    }
    #pragma unroll
    for(int m = 1; m < 16; m <<= 1){
      #pragma unroll
      for(int r = 0; r < 4; r++){ s1[r] += __shfl_xor(s1[r], m); s2[r] += __shfl_xor(s2[r], m); }
    }
    __syncthreads();
    if(l15 == 0){
      #pragma unroll
      for(int r = 0; r < 4; r++){
        red[wave*32 + q4*4 + r]      = s1[r];
        red[wave*32 + 16 + q4*4 + r] = s2[r];
      }
    }
    __syncthreads();
    #pragma unroll
    for(int r = 0; r < 4; r++){
      s1[r] = red[q4*4+r] + red[32+q4*4+r] + red[64+q4*4+r] + red[96+q4*4+r];
      s2[r] = red[16+q4*4+r] + red[48+q4*4+r] + red[80+q4*4+r] + red[112+q4*4+r];
    }
    #pragma unroll
    for(int nt = 0; nt < 2; nt++){
      const int col = (wave + 4*nt)*16 + l15;
      const float g = n2g[col], be = n2b[col];
      #pragma unroll
      for(int r = 0; r < 4; r++){
        const float mu = s1[r]*(1.f/128.f);
        const float var = s2[r]*(1.f/128.f) - mu*mu;
        Abuf[(q4*4+r)*200 + col] =
          __float2bfloat16((xh[nt][r]-mu)*rsqrtf(var+1e-6f)*g + be);
      }
    }
  }
  __syncthreads();

  // ---- fc1 GEMM (11 tiles over 4 waves) + midLN + gelu -> Abuf ----
  {
    bf16x8 af[4];
    #pragma unroll
    for(int s = 0; s < 4; s++) af[s] = *(const bf16x8*)&Abuf[l15*200 + s*32 + q4*8];
    const int ntl = (wave < 3) ? 3 : 2;
    f32x4 fa[3];
    #pragma unroll
    for(int t = 0; t < 3; t++){ fa[t][0]=0.f; fa[t][1]=0.f; fa[t][2]=0.f; fa[t][3]=0.f; }
    for(int t = 0; t < ntl; t++){
      const int col = (wave + 4*t)*16 + l15;
      #pragma unroll
      for(int s = 0; s < 4; s++){
        bf16x8 bw = *(const bf16x8*)&packF1[((s*176 + col)*4 + q4)*8];
        fa[t] = __builtin_amdgcn_mfma_f32_16x16x32_bf16(af[s], bw, fa[t], 0,0,0);
      }
    }
    float s1[4], s2[4];
    #pragma unroll
    for(int r = 0; r < 4; r++){ s1[r]=0.f; s2[r]=0.f; }
    for(int t = 0; t < ntl; t++){
      const int col = (wave + 4*t)*16 + l15;
      if(col < 170){
        const float b1 = fc1_b[col];
        #pragma unroll
        for(int r = 0; r < 4; r++){
          const float vv = fa[t][r] + b1;
          fa[t][r] = vv; s1[r] += vv; s2[r] += vv*vv;
        }
      }
    }
    #pragma unroll
    for(int m = 1; m < 16; m <<= 1){
      #pragma unroll
      for(int r = 0; r < 4; r++){ s1[r] += __shfl_xor(s1[r], m); s2[r] += __shfl_xor(s2[r], m); }
    }
    __syncthreads();
    if(l15 == 0){
      #pragma unroll
      for(int r = 0; r < 4; r++){
        red[wave*32 + q4*4 + r]      = s1[r];
        red[wave*32 + 16 + q4*4 + r] = s2[r];
      }
    }
    __syncthreads();
    #pragma unroll
    for(int r = 0; r < 4; r++){
      s1[r] = red[q4*4+r] + red[32+q4*4+r] + red[64+q4*4+r] + red[96+q4*4+r];
      s2[r] = red[16+q4*4+r] + red[48+q4*4+r] + red[80+q4*4+r] + red[112+q4*4+r];
    }
    const float kA = 0.7978845608028654f, kB = 0.044715f;
    for(int t = 0; t < ntl; t++){
      const int col = (wave + 4*t)*16 + l15;
      if(col < 170){
        const float g = mg[col], be = mb[col];
        #pragma unroll
        for(int r = 0; r < 4; r++){
          const float mu = s1[r]*(1.f/170.f);
          const float var = s2[r]*(1.f/170.f) - mu*mu;
          const float hn = (fa[t][r]-mu)*rsqrtf(var+1e-6f)*g + be;
          const float gl = 0.5f*hn*(1.f + tanhf(kA*(hn + kB*hn*hn*hn)));
          Abuf[(q4*4+r)*200 + col] = __float2bfloat16(gl);
        }
      }
    }
  }
  __syncthreads();

  // ---- fc2 GEMM (K=192) + ls2*res -> xt ----
  {
    bf16x8 af[6];
    #pragma unroll
    for(int s = 0; s < 6; s++) af[s] = *(const bf16x8*)&Abuf[l15*200 + s*32 + q4*8];
    f32x4 oa[2];
    #pragma unroll
    for(int nt = 0; nt < 2; nt++){ oa[nt][0]=0.f; oa[nt][1]=0.f; oa[nt][2]=0.f; oa[nt][3]=0.f; }
    #pragma unroll
    for(int nt = 0; nt < 2; nt++){
      const int col = (wave + 4*nt)*16 + l15;
      #pragma unroll
      for(int s = 0; s < 6; s++){
        bf16x8 bw = *(const bf16x8*)&packF2[((s*128 + col)*4 + q4)*8];
        oa[nt] = __builtin_amdgcn_mfma_f32_16x16x32_bf16(af[s], bw, oa[nt], 0,0,0);
      }
    }
    #pragma unroll
    for(int nt = 0; nt < 2; nt++){
      const int col = (wave + 4*nt)*16 + l15;
      const float bf2 = fc2_b[col], l2 = ls2[col];
      #pragma unroll
      for(int r = 0; r < 4; r++)
        xt_out[prowC[r] + col] = xh[nt][r] + l2*(oa[nt][r] + bf2);
    }
  }
}

// ---- K4: tiled transpose xt (B,HW,C) -> out (B,C,H,W) ----
__global__ void k_tout(const float* __restrict__ xt, float* __restrict__ out){
  __shared__ float tile[32][33];
  const int b = blockIdx.z;
  const int pb = blockIdx.x * 32;
  const int cb = blockIdx.y * 32;
  const int tx = threadIdx.x, ty = threadIdx.y;
  #pragma unroll
  for(int r = 0; r < 32; r += 8)
    tile[ty+r][tx] = xt[(size_t)((b<<14) + pb + ty + r)*128 + cb + tx];
  __syncthreads();
  #pragma unroll
  for(int r = 0; r < 32; r += 8)
    out[(size_t)(b*128 + cb + ty + r)*16384 + pb + tx] = tile[tx][ty+r];
}

extern "C" void kernel_launch(void* const* d_in, const int* in_sizes, int n_in,
                              void* d_out, int out_size, void* d_ws, size_t ws_size,
                              hipStream_t stream){
  const float* x      = (const float*)d_in[0];
  const float* qkv_w  = (const float*)d_in[1];
  const float* qkv_b  = (const float*)d_in[2];
  const float* qg     = (const float*)d_in[3];
  const float* qb     = (const float*)d_in[4];
  const float* kg     = (const float*)d_in[5];
  const float* kb     = (const float*)d_in[6];
  const float* proj_w = (const float*)d_in[7];
  const float* proj_b = (const float*)d_in[8];
  const float* n1g    = (const float*)d_in[9];
  const float* n1b    = (const float*)d_in[10];
  const float* n2g    = (const float*)d_in[11];
  const float* n2b    = (const float*)d_in[12];
  const float* ls1    = (const float*)d_in[13];
  const float* ls2    = (const float*)d_in[14];
  const float* fc1_w  = (const float*)d_in[15];
  const float* fc1_b  = (const float*)d_in[16];
  const float* mg     = (const float*)d_in[17];
  const float* mb     = (const float*)d_in[18];
  const float* fc2_w  = (const float*)d_in[19];
  const float* fc2_b  = (const float*)d_in[20];

  float* ws  = (float*)d_ws;
  float* xt  = ws;
  float* kcb = ws + 4194304;
  float* vcb = ws + 5242880;
  BF* pk     = (BF*)(ws + 6291456);
  BF* packQ  = pk;
  BF* packK  = pk + 16384;
  BF* packV  = pk + 32768;
  BF* packP  = pk + 49152;
  BF* packF1 = pk + 65536;
  BF* packF2 = pk + 88064;

  dim3 tgrid(512, 4, 2), tblk(32, 8);
  k_tin <<<tgrid, tblk, 0, stream>>>(x, xt);
  k_wt  <<<440, 256, 0, stream>>>(qkv_w, proj_w, fc1_w, fc2_w, pk);
  k_kv  <<<512, 128, 0, stream>>>(xt, packK, packV, qkv_b, kg, kb, n1g, n1b, kcb, vcb);
  k_cell<<<2048, 256, 0, stream>>>(xt, packQ, packP, packF1, packF2,
                                   qkv_b, qg, qb, n1g, n1b, proj_b, ls1, ls2,
                                   n2g, n2b, fc1_b, mg, mb, fc2_b,
                                   kcb, vcb, xt);
  k_tout<<<tgrid, tblk, 0, stream>>>(xt, (float*)d_out);
}